// Round 5
// baseline (903.466 us; speedup 1.0000x reference)
//
#include <hip/hip_runtime.h>
#include <hip/hip_bf16.h>
#include <math.h>

namespace {

constexpr int Bn = 256;
constexpr int Tn = 128;
constexpr int Dn = 256;
constexpr int Hn = 512;
constexpr int BT = Bn * Tn;

constexpr int AP = 776;   // scan LDS K-stride in bf16 (768+8)
constexpr int GP = 264;   // gamma LDS K-stride in bf16 (256+8)
constexpr int GS = 68;    // gate tile stride (floats)
constexpr unsigned KC = 2654435769u;  // odd -> bijective key mixer

typedef short bf8_t __attribute__((ext_vector_type(8)));
typedef float f32x4 __attribute__((ext_vector_type(4)));
typedef unsigned int u32x4 __attribute__((ext_vector_type(4)));

__device__ __forceinline__ float sigm(float v) { return 1.0f / (1.0f + expf(-v)); }

__device__ __forceinline__ unsigned short f2bf(float f) {
  union { __hip_bfloat16 h; unsigned short u; } v;
  v.h = __float2bfloat16(f);
  return v.u;
}
__device__ __forceinline__ float bf2f(unsigned short u) {
  union { unsigned int i; float f; } v;
  v.i = ((unsigned int)u) << 16;
  return v.f;
}

// run-nonce bump (graph replays re-execute this -> per-run unique exchange keys)
__global__ void k_nonce(unsigned* __restrict__ np) {
  if (threadIdx.x == 0 && blockIdx.x == 0) np[0] = np[0] + 1u;
}

// dt fp32 -> bf16 (flat copy)
__global__ __launch_bounds__(256) void k_cvt_dt(const float* __restrict__ src,
                                                unsigned short* __restrict__ dst) {
  size_t i = (size_t)blockIdx.x * 256 + threadIdx.x;
  float4 v = ((const float4*)src)[i];
  uint2 o;
  o.x = (unsigned)f2bf(v.x) | ((unsigned)f2bf(v.y) << 16);
  o.y = (unsigned)f2bf(v.z) | ((unsigned)f2bf(v.w) << 16);
  ((uint2*)dst)[i] = o;
}

// w_gh [Dn,Hn] fp32 -> wT bf16 [Hn,Dn] (transpose)
__global__ __launch_bounds__(256) void k_cvt_wgh(const float* __restrict__ w,
                                                 unsigned short* __restrict__ wT) {
  int o = blockIdx.x * 256 + threadIdx.x;  // = n*Dn + k
  int n = o >> 8, k = o & 255;
  wT[o] = f2bf(w[(size_t)k * Hn + n]);
}

// gamma_h via MFMA: [BT,256]bf16 @ [256,512] -> exp(-relu(.+bias)) into [T,B,H] fp32
__global__ __launch_bounds__(256) void k_gamma_mfma(
    const unsigned short* __restrict__ dtb,  // [BT, Dn] bf16
    const unsigned short* __restrict__ wT,   // [Hn, Dn] bf16
    const float* __restrict__ bias,          // [Hn]
    float* __restrict__ outg) {              // [T,B,H]
  __shared__ unsigned short Abf[128 * GP];  // 67.6 KB
  __shared__ unsigned short Bbf[64 * GP];   // 33.8 KB
  int tid = threadIdx.x;
  int n0 = blockIdx.x * 64;
  int bb = blockIdx.y;  // one 128-row M-block == one batch
  const u32x4* asrc = (const u32x4*)(dtb + (size_t)bb * 128 * Dn);
#pragma unroll
  for (int i = 0; i < 16; ++i) {
    int c = tid + 256 * i;
    *(u32x4*)(&Abf[(size_t)(c >> 5) * GP + (c & 31) * 8]) = asrc[c];
  }
  const u32x4* bsrc = (const u32x4*)(wT + (size_t)n0 * Dn);
#pragma unroll
  for (int i = 0; i < 8; ++i) {
    int c = tid + 256 * i;
    *(u32x4*)(&Bbf[(size_t)(c >> 5) * GP + (c & 31) * 8]) = bsrc[c];
  }
  int lane = tid & 63, w = tid >> 6;
  int ln = lane & 15, qd = lane >> 4;
  float bn[4];
#pragma unroll
  for (int j = 0; j < 4; ++j) bn[j] = bias[n0 + 16 * j + ln];
  __syncthreads();
  f32x4 acc[2][4] = {};
  const unsigned short* a0 = &Abf[(size_t)(32 * w + ln) * GP + qd * 8];
  const unsigned short* a1 = &Abf[(size_t)(32 * w + 16 + ln) * GP + qd * 8];
#pragma unroll
  for (int ks = 0; ks < 8; ++ks) {
    bf8_t af0 = *(const bf8_t*)(a0 + ks * 32);
    bf8_t af1 = *(const bf8_t*)(a1 + ks * 32);
#pragma unroll
    for (int j = 0; j < 4; ++j) {
      bf8_t bf = *(const bf8_t*)(&Bbf[(size_t)(16 * j + ln) * GP + qd * 8 + ks * 32]);
      acc[0][j] = __builtin_amdgcn_mfma_f32_16x16x32_bf16(af0, bf, acc[0][j], 0, 0, 0);
      acc[1][j] = __builtin_amdgcn_mfma_f32_16x16x32_bf16(af1, bf, acc[1][j], 0, 0, 0);
    }
  }
#pragma unroll
  for (int mt = 0; mt < 2; ++mt)
#pragma unroll
    for (int r = 0; r < 4; ++r) {
      int t = 32 * w + 16 * mt + qd * 4 + r;
#pragma unroll
      for (int j = 0; j < 4; ++j) {
        float v = acc[mt][j][r] + bn[j];
        outg[((size_t)t * Bn + bb) * Hn + n0 + 16 * j + ln] = expf(-fmaxf(v, 0.f));
      }
    }
}

// gamma_x GEMM fused with imputation; writes xs fp32 to xhats [T,B,D] and bf16 copy
__global__ __launch_bounds__(256) void k_xs(const float* __restrict__ dt,
                                            const float* __restrict__ w,
                                            const float* __restrict__ bias,
                                            const float* __restrict__ x,
                                            const float* __restrict__ mask,
                                            const float* __restrict__ xmean,
                                            float* __restrict__ out_xs,
                                            unsigned short* __restrict__ out_bf) {
  __shared__ float As[64][17];
  __shared__ float Bs[16][64];
  int tid = threadIdx.x;
  int tx = tid & 15, ty = tid >> 4;
  int m0 = blockIdx.y * 64, n0 = blockIdx.x * 64;
  float acc[4][4] = {};
  for (int k0 = 0; k0 < Dn; k0 += 16) {
    {
      int ml = tid >> 2, kk = (tid & 3) * 4;
      float4 v = *(const float4*)(dt + (size_t)(m0 + ml) * Dn + k0 + kk);
      As[ml][kk + 0] = v.x; As[ml][kk + 1] = v.y;
      As[ml][kk + 2] = v.z; As[ml][kk + 3] = v.w;
    }
    {
      int kb = (tid >> 6) * 4, nl = tid & 63;
#pragma unroll
      for (int r = 0; r < 4; ++r)
        Bs[kb + r][nl] = w[(size_t)(k0 + kb + r) * Dn + n0 + nl];
    }
    __syncthreads();
#pragma unroll
    for (int kk = 0; kk < 16; ++kk) {
      float a[4], b[4];
#pragma unroll
      for (int i = 0; i < 4; ++i) a[i] = As[ty + 16 * i][kk];
#pragma unroll
      for (int j = 0; j < 4; ++j) b[j] = Bs[kk][tx + 16 * j];
#pragma unroll
      for (int i = 0; i < 4; ++i)
#pragma unroll
        for (int j = 0; j < 4; ++j) acc[i][j] += a[i] * b[j];
    }
    __syncthreads();
  }
#pragma unroll
  for (int j = 0; j < 4; ++j) {
    int d = n0 + tx + 16 * j;
    float bv = bias[d];
    float xm = xmean[d];
#pragma unroll
    for (int i = 0; i < 4; ++i) {
      int m = m0 + ty + 16 * i;
      int b = m >> 7, tt = m & (Tn - 1);
      float g = expf(-fmaxf(acc[i][j] + bv, 0.0f));
      float imput = (tt == 0) ? xm
                              : g * x[(size_t)(m - 1) * Dn + d] + (1.0f - g) * xm;
      float xv = x[(size_t)m * Dn + d];
      float mv = mask[(size_t)m * Dn + d];
      float xsv = xv * mv + (1.0f - mv) * imput;
      size_t oi = ((size_t)tt * Bn + b) * Dn + d;
      out_xs[oi] = xsv;
      out_bf[oi] = f2bf(xsv);
    }
  }
}

// Tagged hdec init: buf0[i] = {pay, pay^key0} (valid step-0 data);
// buf1[i] = {0, key1^1} (guaranteed-INVALID for step 1's key -> pollers retry
// until real step-0 producers overwrite it). One pair i = (b, p) = 2 h-units.
__global__ __launch_bounds__(256) void k_init(const float* __restrict__ h0,
                                              const float* __restrict__ gammaT,
                                              unsigned int* __restrict__ hdec,
                                              const unsigned* __restrict__ np) {
  int i = blockIdx.x * 256 + threadIdx.x;  // pair index in [0, Bn*256)
  unsigned nb = np[0] << 8;
  unsigned key0 = nb * KC;
  unsigned key1 = (nb + 1u) * KC;
  int h = (i & 255) * 2;
  int b = i >> 8;
  float g0 = gammaT[(size_t)b * Hn + h];
  float g1 = gammaT[(size_t)b * Hn + h + 1];
  unsigned pay = (unsigned)f2bf(h0[h] * g0) | ((unsigned)f2bf(h0[h + 1] * g1) << 16);
  uint2* buf0 = (uint2*)hdec;
  uint2* buf1 = buf0 + (size_t)Bn * 256;
  uint2 v0; v0.x = pay; v0.y = pay ^ key0;
  uint2 v1; v1.x = 0u;  v1.y = key1 ^ 1u;
  buf0[i] = v0;
  buf1[i] = v1;
}

// Persistent MFMA scan: 256 blocks, 8 groups x 32 blocks (bt=blockIdx&7).
// Block owns 32 batches x 16 h-units. Weights bf16 in LDS.
//
// FLAG-FREE EXCHANGE (round 3, proven): tagged dwordx2 {pay, pay^key(run,t)},
// sc0 sc1 fire-and-forget stores; consumers poll data and validate tags.
//
// ROUND 5 (surgical, round-3 skeleton unchanged: 2 __syncthreads, single
// 24-ks MFMA block): (1) poll loads issued FIRST at loop top, in flight
// while the register-prefetched xs tile is written to LDS — the compiler's
// conservative vmcnt before those ds_writes consolidates [t-1 store drain,
// xs data, polls] into ONE ~700cy wait instead of round-3's serial
// ~400+700cy; (2) xs(t+1) loads issued in the epilogue (hide under LSTM);
// (3) gam/tp loads moved AFTER validation (issue post-validate, consumed
// ~1500cy later in the LSTM -> HBM latency never sits in the poll path);
// (4) gamma carried across steps (1 gammaT read/step).
__global__ __launch_bounds__(256, 1) void k_scan(
    const unsigned short* __restrict__ xs_bf,  // [T,B,D] bf16
    const float* __restrict__ gammaT,          // [T,B,H] fp32
    unsigned int* __restrict__ hdec_tag,       // [2][B][256] x {pay,chk}
    unsigned short* __restrict__ h_bf,         // [T,B,H] bf16 (h1 history)
    const float* __restrict__ c0,              // [H]
    const float* __restrict__ W_ih,            // [4H, D] fp32
    const float* __restrict__ W_hh,            // [4H, H] fp32
    const float* __restrict__ b_ih, const float* __restrict__ b_hh,
    const float* __restrict__ tp,              // [B,T]
    const float* __restrict__ w_t, const float* __restrict__ h_t,
    const unsigned* __restrict__ np) {
  __shared__ unsigned short Wlds[64 * AP];  // 97 KB: 64 gate cols x 768 K
  __shared__ unsigned short Alds[32 * AP];  // 48.5 KB: 32 batches x 768 K
  __shared__ float Gs[32 * GS];             // 8.7 KB
  int tid = threadIdx.x;
  int bt = blockIdx.x & 7;   // batch group
  int ht = blockIdx.x >> 3;  // h tile [0,32)
  int b0 = bt * 32, h0b = ht * 16;
  unsigned nb = np[0] << 8;  // key base for this run

  // --- stage weights once: col c = g*16 + hu, K-major bf16
  for (int idx = tid; idx < 64 * 192; idx += 256) {
    int c = idx / 192;
    int s = idx - c * 192;
    int kg = s * 4;
    int g = c >> 4, hu = c & 15;
    int jw = g * Hn + h0b + hu;
    float4 wv;
    if (kg < Dn) wv = *(const float4*)(W_ih + (size_t)jw * Dn + kg);
    else         wv = *(const float4*)(W_hh + (size_t)jw * Hn + (kg - Dn));
    unsigned int u01 = (unsigned int)f2bf(wv.x) | ((unsigned int)f2bf(wv.y) << 16);
    unsigned int u23 = (unsigned int)f2bf(wv.z) | ((unsigned int)f2bf(wv.w) << 16);
    *(unsigned int*)(&Wlds[(size_t)c * AP + kg]) = u01;
    *(unsigned int*)(&Wlds[(size_t)c * AP + kg + 2]) = u23;
  }

  // --- per-thread cell hoists: thread -> (batch bl, h-pair hp)
  int bl = tid >> 3;
  int hp = tid & 7;
  int hloc = 2 * hp;
  int b = b0 + bl;
  float bias[4][2];
#pragma unroll
  for (int g = 0; g < 4; ++g)
#pragma unroll
    for (int u = 0; u < 2; ++u) {
      int jw = g * Hn + h0b + hloc + u;
      bias[g][u] = b_ih[jw] + b_hh[jw];
    }
  float wtv[2], htv[2], creg[2];
#pragma unroll
  for (int u = 0; u < 2; ++u) {
    wtv[u] = w_t[h0b + hloc + u];
    htv[u] = h_t[h0b + hloc + u];
    creg[u] = c0[h0b + hloc + u];
  }

  // --- MFMA lane mapping
  int lane = tid & 63, wv4 = tid >> 6;
  int ln = lane & 15, qd = lane >> 4;
  int mrow = 16 * (wv4 & 1) + ln;
  int ncol = 32 * (wv4 >> 1);
  const unsigned short* abase = &Alds[(size_t)mrow * AP + qd * 8];
  const unsigned short* bb0 = &Wlds[(size_t)(ncol + ln) * AP + qd * 8];
  const unsigned short* bb1 = &Wlds[(size_t)(ncol + 16 + ln) * AP + qd * 8];
  // producer store address (fixed h-pair, alternating parity)
  unsigned int* pstore =
      hdec_tag + ((size_t)b * 256 + 8 * (size_t)ht + hp) * 2;

  // --- prologue: xs(0) register prefetch + gamma(0) carry
  float4 xr[4];
  {
    const float4* xsrc = (const float4*)(xs_bf + (size_t)b0 * Dn);
#pragma unroll
    for (int i = 0; i < 4; ++i) xr[i] = xsrc[tid + 256 * i];
  }
  float2 gamc = *(const float2*)(gammaT + (size_t)b * Hn + h0b + hloc);  // t=0
  __syncthreads();  // weights staged

  for (int t = 0; t < Tn; ++t) {
    unsigned key = (nb + (unsigned)t) * KC;

    // --- A: issue poll round-0 loads FIRST (in flight during xs staging)
    const unsigned int* hsrc =
        hdec_tag + (size_t)(t & 1) * (Bn * 256 * 2) + (size_t)b0 * 256 * 2;
    u32x4 hv[16];
#pragma unroll
    for (int i = 0; i < 16; ++i) {
      int q = tid + 256 * i;
      const void* p = hsrc + (size_t)q * 4;  // dwordx4 = 2 tagged pairs
      asm volatile("global_load_dwordx4 %0, %1, off sc0 sc1"
                   : "=&v"(hv[i]) : "v"(p) : "memory");
    }

    // --- B: write prefetched xs(t) regs -> LDS (consolidated vmcnt wait here)
#pragma unroll
    for (int i = 0; i < 4; ++i) {
      int c = tid + 256 * i;
      *(float4*)(&Alds[(size_t)(c >> 5) * AP + (c & 31) * 8]) = xr[i];
    }

    // --- C: validate tags (data already arrived during staging)
    {
      asm volatile("s_waitcnt vmcnt(0)" ::: "memory");
      __builtin_amdgcn_sched_barrier(0);
      int ok = 1;
#pragma unroll
      for (int i = 0; i < 16; ++i)
        ok &= (hv[i][1] == (hv[i][0] ^ key)) & (hv[i][3] == (hv[i][2] ^ key));
      int spins = 0;
      while (!ok) {
        if (++spins > 300000) break;  // bounded: visible failure, never hang
        __builtin_amdgcn_s_sleep(1);
#pragma unroll
        for (int i = 0; i < 16; ++i) {
          int q = tid + 256 * i;
          const void* p = hsrc + (size_t)q * 4;
          asm volatile("global_load_dwordx4 %0, %1, off sc0 sc1"
                       : "=&v"(hv[i]) : "v"(p) : "memory");
        }
        asm volatile("s_waitcnt vmcnt(0)" ::: "memory");
        __builtin_amdgcn_sched_barrier(0);
        ok = 1;
#pragma unroll
        for (int i = 0; i < 16; ++i)
          ok &= (hv[i][1] == (hv[i][0] ^ key)) & (hv[i][3] == (hv[i][2] ^ key));
      }
    }

    // --- D: h payloads -> LDS (k 256..767)
#pragma unroll
    for (int i = 0; i < 16; ++i) {
      int q = tid + 256 * i;
      int blr = q >> 7;            // batch row (128 chunks per batch)
      int p0 = (q & 127) * 2;      // first pair index in chunk
      uint2 pv; pv.x = hv[i][0]; pv.y = hv[i][2];
      *(uint2*)(&Alds[(size_t)blr * AP + 256 + 2 * p0]) = pv;
    }

    // --- E: epilogue operands issued now; consumed ~1500cy later in LSTM
    float2 gam0 = gamc;
    float2 gam1 = (t + 1 < Tn)
        ? *(const float2*)(gammaT + ((size_t)(t + 1) * Bn + b) * Hn + h0b + hloc)
        : make_float2(0.f, 0.f);
    float tpv = tp[(size_t)b * Tn + t];

    __syncthreads();

    // --- F: MFMA: 24 k-steps x 2 n-tiles -> 16M x 32N per wave
    f32x4 acc0 = {0.f, 0.f, 0.f, 0.f};
    f32x4 acc1 = {0.f, 0.f, 0.f, 0.f};
#pragma unroll
    for (int ks = 0; ks < 24; ++ks) {
      bf8_t a = *(const bf8_t*)(abase + ks * 32);
      bf8_t b0f = *(const bf8_t*)(bb0 + ks * 32);
      bf8_t b1f = *(const bf8_t*)(bb1 + ks * 32);
      acc0 = __builtin_amdgcn_mfma_f32_16x16x32_bf16(a, b0f, acc0, 0, 0, 0);
      acc1 = __builtin_amdgcn_mfma_f32_16x16x32_bf16(a, b1f, acc1, 0, 0, 0);
    }

    // --- gates -> LDS (C layout: col=lane&15, row=quad*4+reg)
#pragma unroll
    for (int r = 0; r < 4; ++r) {
      int grow = 16 * (wv4 & 1) + qd * 4 + r;
      Gs[grow * GS + ncol + ln] = acc0[r];
      Gs[grow * GS + ncol + 16 + ln] = acc1[r];
    }
    __syncthreads();

    // --- LSTM cell: 2 adjacent-h cells per thread
    {
      float2 ip = *(const float2*)(&Gs[bl * GS + hloc]);
      float2 fp = *(const float2*)(&Gs[bl * GS + 16 + hloc]);
      float2 gp = *(const float2*)(&Gs[bl * GS + 32 + hloc]);
      float2 op = *(const float2*)(&Gs[bl * GS + 48 + hloc]);
      float h1[2], hd[2];
      float gam0a[2] = {gam0.x, gam0.y}, gam1a[2] = {gam1.x, gam1.y};
      float ipa[2] = {ip.x, ip.y}, fpa[2] = {fp.x, fp.y};
      float gpa[2] = {gp.x, gp.y}, opa[2] = {op.x, op.y};
#pragma unroll
      for (int u = 0; u < 2; ++u) {
        float c1 = sigm(fpa[u] + bias[1][u]) * (creg[u] * gam0a[u]) +
                   sigm(ipa[u] + bias[0][u]) * tanhf(gpa[u] + bias[2][u]);
        float gtv = sigm(tpv * wtv[u] + htv[u]);
        h1[u] = gtv * sigm(opa[u] + bias[3][u]) * tanhf(c1);
        creg[u] = gtv * c1;
        hd[u] = h1[u] * gam1a[u];
      }
      // fire-and-forget tagged store for step t+1 (no drain, no flag)
      if (t + 1 < Tn) {
        unsigned keyn = (nb + (unsigned)(t + 1)) * KC;
        unsigned dpk =
            (unsigned)f2bf(hd[0]) | ((unsigned)f2bf(hd[1]) << 16);
        unsigned long long val =
            (unsigned long long)dpk | ((unsigned long long)(dpk ^ keyn) << 32);
        const void* dp = pstore + (size_t)((t + 1) & 1) * (Bn * 256 * 2);
        asm volatile("global_store_dwordx2 %0, %1, off sc0 sc1"
                     :: "v"(dp), "v"(val) : "memory");
      }
      // h1 history (cached store; consumed only by k_head)
      unsigned hpk =
          (unsigned)f2bf(h1[0]) | ((unsigned)f2bf(h1[1]) << 16);
      *(unsigned int*)(h_bf + ((size_t)t * Bn + b) * Hn + h0b + hloc) = hpk;
    }

    // --- G: prefetch xs(t+1) into regs (latency hides under loop tail)
    if (t + 1 < Tn) {
      const float4* xsrc =
          (const float4*)(xs_bf + ((size_t)(t + 1) * Bn + b0) * Dn);
#pragma unroll
      for (int i = 0; i < 4; ++i) xr[i] = xsrc[tid + 256 * i];
    }
    gamc = gam1;
  }
}

// Batched output head over all (t,b) rows; h1 read from bf16 history
__global__ __launch_bounds__(256) void k_head(const unsigned short* __restrict__ h_bf,
                                              const float* __restrict__ W1,
                                              const float* __restrict__ b1,
                                              const float* __restrict__ W2,
                                              const float* __restrict__ b2,
                                              float* __restrict__ outs) {
  __shared__ float sW1[Hn * 10];
  for (int i = threadIdx.x; i < Hn * 10; i += 256) sW1[i] = W1[i];
  __syncthreads();
  int idx = blockIdx.x * 256 + threadIdx.x;  // idx = tt*Bn + b
  const uint4* row = (const uint4*)(h_bf + (size_t)idx * Hn);
  float z1[10];
#pragma unroll
  for (int k = 0; k < 10; ++k) z1[k] = b1[k];
  for (int hq = 0; hq < Hn / 8; ++hq) {
    uint4 u = row[hq];
    float hv[8];
    hv[0] = bf2f(u.x & 0xffff); hv[1] = bf2f(u.x >> 16);
    hv[2] = bf2f(u.y & 0xffff); hv[3] = bf2f(u.y >> 16);
    hv[4] = bf2f(u.z & 0xffff); hv[5] = bf2f(u.z >> 16);
    hv[6] = bf2f(u.w & 0xffff); hv[7] = bf2f(u.w >> 16);
    int hb = hq * 8;
#pragma unroll
    for (int c = 0; c < 8; ++c)
#pragma unroll
      for (int k = 0; k < 10; ++k) z1[k] += hv[c] * sW1[(hb + c) * 10 + k];
  }
#pragma unroll
  for (int k = 0; k < 10; ++k) z1[k] = sigm(z1[k]);
  float z2[2];
#pragma unroll
  for (int c = 0; c < 2; ++c) {
    float v = b2[c];
#pragma unroll
    for (int k = 0; k < 10; ++k) v += z1[k] * W2[k * 2 + c];
    z2[c] = sigm(v);
  }
  float mx = fmaxf(z2[0], z2[1]);
  float e0 = expf(z2[0] - mx), e1 = expf(z2[1] - mx);
  float s = e0 + e1;
  outs[(size_t)idx * 2 + 0] = e0 / s;
  outs[(size_t)idx * 2 + 1] = e1 / s;
}

}  // namespace

extern "C" void kernel_launch(void* const* d_in, const int* in_sizes, int n_in,
                              void* d_out, int out_size, void* d_ws,
                              size_t ws_size, hipStream_t stream) {
  (void)in_sizes; (void)n_in; (void)out_size; (void)ws_size;
  const float* x     = (const float*)d_in[0];
  const float* dt    = (const float*)d_in[1];
  const float* mask  = (const float*)d_in[2];
  const float* tp    = (const float*)d_in[3];
  const float* xmean = (const float*)d_in[4];
  const float* h0    = (const float*)d_in[5];
  const float* c0    = (const float*)d_in[6];
  const float* w_gx  = (const float*)d_in[7];
  const float* h_gx  = (const float*)d_in[8];
  const float* w_gh  = (const float*)d_in[9];
  const float* h_gh  = (const float*)d_in[10];
  const float* w_t   = (const float*)d_in[11];
  const float* h_t   = (const float*)d_in[12];
  const float* W_ih  = (const float*)d_in[13];
  const float* W_hh  = (const float*)d_in[14];
  const float* b_ih  = (const float*)d_in[15];
  const float* b_hh  = (const float*)d_in[16];
  const float* oW1   = (const float*)d_in[17];
  const float* ob1   = (const float*)d_in[18];
  const float* oW2   = (const float*)d_in[19];
  const float* ob2   = (const float*)d_in[20];

  float* out  = (float*)d_out;
  float* outs = out;                        // [T,B,2]
  float* xhat = out + (size_t)Tn * Bn * 2;  // [T,B,D] fp32 (output 1)

  float* ws = (float*)d_ws;
  float* gammaT = ws;  // [T,B,H] fp32: 67.1 MB
  unsigned short* xs_bf  = (unsigned short*)(gammaT + (size_t)BT * Hn);  // 16.8 MB
  unsigned short* h_bf   = xs_bf + (size_t)BT * Dn;                      // 33.6 MB
  unsigned int* hdec_tag = (unsigned int*)(h_bf + (size_t)BT * Hn);      // 1 MB
  unsigned short* dt_bf  = (unsigned short*)(hdec_tag + 2 * (size_t)Bn * 256 * 2);
  unsigned short* wghT   = dt_bf + (size_t)BT * Dn;                      // 0.26 MB
  unsigned* np = (unsigned*)(wghT + (size_t)Hn * Dn);                    // 4 B nonce

  k_nonce<<<1, 64, 0, stream>>>(np);
  k_cvt_dt<<<BT * Dn / 4 / 256, 256, 0, stream>>>(dt, dt_bf);
  k_cvt_wgh<<<Hn * Dn / 256, 256, 0, stream>>>(w_gh, wghT);
  k_gamma_mfma<<<dim3(Hn / 64, Bn), 256, 0, stream>>>(dt_bf, wghT, h_gh, gammaT);
  k_xs<<<dim3(Dn / 64, BT / 64), 256, 0, stream>>>(dt, w_gx, h_gx, x, mask,
                                                   xmean, xhat, xs_bf);
  k_init<<<(Bn * 256) / 256, 256, 0, stream>>>(h0, gammaT, hdec_tag, np);
  k_scan<<<256, 256, 0, stream>>>(xs_bf, gammaT, hdec_tag, h_bf, c0, W_ih, W_hh,
                                  b_ih, b_hh, tp, w_t, h_t, np);
  k_head<<<BT / 256, 256, 0, stream>>>(h_bf, oW1, ob1, oW2, ob2, outs);
}

// Round 6
// 813.455 us; speedup vs baseline: 1.1107x; 1.1107x over previous
//
#include <hip/hip_runtime.h>
#include <hip/hip_bf16.h>
#include <math.h>

namespace {

constexpr int Bn = 256;
constexpr int Tn = 128;
constexpr int Dn = 256;
constexpr int Hn = 512;
constexpr int BT = Bn * Tn;

constexpr int AP = 776;   // scan LDS K-stride in bf16 (768+8)
constexpr int GP = 264;   // gamma LDS K-stride in bf16 (256+8)
constexpr int GS = 68;    // gate tile stride (floats)
constexpr unsigned KC = 2654435769u;  // odd -> bijective key mixer

typedef short bf8_t __attribute__((ext_vector_type(8)));
typedef float f32x4 __attribute__((ext_vector_type(4)));
typedef unsigned int u32x4 __attribute__((ext_vector_type(4)));

__device__ __forceinline__ float sigm(float v) { return 1.0f / (1.0f + expf(-v)); }

__device__ __forceinline__ unsigned short f2bf(float f) {
  union { __hip_bfloat16 h; unsigned short u; } v;
  v.h = __float2bfloat16(f);
  return v.u;
}
__device__ __forceinline__ float bf2f(unsigned short u) {
  union { unsigned int i; float f; } v;
  v.i = ((unsigned int)u) << 16;
  return v.f;
}

// run-nonce bump (graph replays re-execute this -> per-run unique exchange keys)
__global__ void k_nonce(unsigned* __restrict__ np) {
  if (threadIdx.x == 0 && blockIdx.x == 0) np[0] = np[0] + 1u;
}

// dt fp32 -> bf16 (flat copy)
__global__ __launch_bounds__(256) void k_cvt_dt(const float* __restrict__ src,
                                                unsigned short* __restrict__ dst) {
  size_t i = (size_t)blockIdx.x * 256 + threadIdx.x;
  float4 v = ((const float4*)src)[i];
  uint2 o;
  o.x = (unsigned)f2bf(v.x) | ((unsigned)f2bf(v.y) << 16);
  o.y = (unsigned)f2bf(v.z) | ((unsigned)f2bf(v.w) << 16);
  ((uint2*)dst)[i] = o;
}

// w_gh [Dn,Hn] fp32 -> wT bf16 [Hn,Dn] (transpose)
__global__ __launch_bounds__(256) void k_cvt_wgh(const float* __restrict__ w,
                                                 unsigned short* __restrict__ wT) {
  int o = blockIdx.x * 256 + threadIdx.x;  // = n*Dn + k
  int n = o >> 8, k = o & 255;
  wT[o] = f2bf(w[(size_t)k * Hn + n]);
}

// gamma_h via MFMA: [BT,256]bf16 @ [256,512] -> exp(-relu(.+bias)) into [T,B,H] fp32
__global__ __launch_bounds__(256) void k_gamma_mfma(
    const unsigned short* __restrict__ dtb,  // [BT, Dn] bf16
    const unsigned short* __restrict__ wT,   // [Hn, Dn] bf16
    const float* __restrict__ bias,          // [Hn]
    float* __restrict__ outg) {              // [T,B,H]
  __shared__ unsigned short Abf[128 * GP];  // 67.6 KB
  __shared__ unsigned short Bbf[64 * GP];   // 33.8 KB
  int tid = threadIdx.x;
  int n0 = blockIdx.x * 64;
  int bb = blockIdx.y;  // one 128-row M-block == one batch
  const u32x4* asrc = (const u32x4*)(dtb + (size_t)bb * 128 * Dn);
#pragma unroll
  for (int i = 0; i < 16; ++i) {
    int c = tid + 256 * i;
    *(u32x4*)(&Abf[(size_t)(c >> 5) * GP + (c & 31) * 8]) = asrc[c];
  }
  const u32x4* bsrc = (const u32x4*)(wT + (size_t)n0 * Dn);
#pragma unroll
  for (int i = 0; i < 8; ++i) {
    int c = tid + 256 * i;
    *(u32x4*)(&Bbf[(size_t)(c >> 5) * GP + (c & 31) * 8]) = bsrc[c];
  }
  int lane = tid & 63, w = tid >> 6;
  int ln = lane & 15, qd = lane >> 4;
  float bn[4];
#pragma unroll
  for (int j = 0; j < 4; ++j) bn[j] = bias[n0 + 16 * j + ln];
  __syncthreads();
  f32x4 acc[2][4] = {};
  const unsigned short* a0 = &Abf[(size_t)(32 * w + ln) * GP + qd * 8];
  const unsigned short* a1 = &Abf[(size_t)(32 * w + 16 + ln) * GP + qd * 8];
#pragma unroll
  for (int ks = 0; ks < 8; ++ks) {
    bf8_t af0 = *(const bf8_t*)(a0 + ks * 32);
    bf8_t af1 = *(const bf8_t*)(a1 + ks * 32);
#pragma unroll
    for (int j = 0; j < 4; ++j) {
      bf8_t bf = *(const bf8_t*)(&Bbf[(size_t)(16 * j + ln) * GP + qd * 8 + ks * 32]);
      acc[0][j] = __builtin_amdgcn_mfma_f32_16x16x32_bf16(af0, bf, acc[0][j], 0, 0, 0);
      acc[1][j] = __builtin_amdgcn_mfma_f32_16x16x32_bf16(af1, bf, acc[1][j], 0, 0, 0);
    }
  }
#pragma unroll
  for (int mt = 0; mt < 2; ++mt)
#pragma unroll
    for (int r = 0; r < 4; ++r) {
      int t = 32 * w + 16 * mt + qd * 4 + r;
#pragma unroll
      for (int j = 0; j < 4; ++j) {
        float v = acc[mt][j][r] + bn[j];
        outg[((size_t)t * Bn + bb) * Hn + n0 + 16 * j + ln] = expf(-fmaxf(v, 0.f));
      }
    }
}

// gamma_x GEMM fused with imputation; writes xs fp32 to xhats [T,B,D] and bf16 copy
__global__ __launch_bounds__(256) void k_xs(const float* __restrict__ dt,
                                            const float* __restrict__ w,
                                            const float* __restrict__ bias,
                                            const float* __restrict__ x,
                                            const float* __restrict__ mask,
                                            const float* __restrict__ xmean,
                                            float* __restrict__ out_xs,
                                            unsigned short* __restrict__ out_bf) {
  __shared__ float As[64][17];
  __shared__ float Bs[16][64];
  int tid = threadIdx.x;
  int tx = tid & 15, ty = tid >> 4;
  int m0 = blockIdx.y * 64, n0 = blockIdx.x * 64;
  float acc[4][4] = {};
  for (int k0 = 0; k0 < Dn; k0 += 16) {
    {
      int ml = tid >> 2, kk = (tid & 3) * 4;
      float4 v = *(const float4*)(dt + (size_t)(m0 + ml) * Dn + k0 + kk);
      As[ml][kk + 0] = v.x; As[ml][kk + 1] = v.y;
      As[ml][kk + 2] = v.z; As[ml][kk + 3] = v.w;
    }
    {
      int kb = (tid >> 6) * 4, nl = tid & 63;
#pragma unroll
      for (int r = 0; r < 4; ++r)
        Bs[kb + r][nl] = w[(size_t)(k0 + kb + r) * Dn + n0 + nl];
    }
    __syncthreads();
#pragma unroll
    for (int kk = 0; kk < 16; ++kk) {
      float a[4], b[4];
#pragma unroll
      for (int i = 0; i < 4; ++i) a[i] = As[ty + 16 * i][kk];
#pragma unroll
      for (int j = 0; j < 4; ++j) b[j] = Bs[kk][tx + 16 * j];
#pragma unroll
      for (int i = 0; i < 4; ++i)
#pragma unroll
        for (int j = 0; j < 4; ++j) acc[i][j] += a[i] * b[j];
    }
    __syncthreads();
  }
#pragma unroll
  for (int j = 0; j < 4; ++j) {
    int d = n0 + tx + 16 * j;
    float bv = bias[d];
    float xm = xmean[d];
#pragma unroll
    for (int i = 0; i < 4; ++i) {
      int m = m0 + ty + 16 * i;
      int b = m >> 7, tt = m & (Tn - 1);
      float g = expf(-fmaxf(acc[i][j] + bv, 0.0f));
      float imput = (tt == 0) ? xm
                              : g * x[(size_t)(m - 1) * Dn + d] + (1.0f - g) * xm;
      float xv = x[(size_t)m * Dn + d];
      float mv = mask[(size_t)m * Dn + d];
      float xsv = xv * mv + (1.0f - mv) * imput;
      size_t oi = ((size_t)tt * Bn + b) * Dn + d;
      out_xs[oi] = xsv;
      out_bf[oi] = f2bf(xsv);
    }
  }
}

// Tagged hdec init: buf0[i] = {pay, pay^key0} (valid step-0 data);
// buf1[i] = {0, key1^1} (guaranteed-INVALID for step 1's key -> pollers retry
// until real step-0 producers overwrite it). One pair i = (b, p) = 2 h-units.
__global__ __launch_bounds__(256) void k_init(const float* __restrict__ h0,
                                              const float* __restrict__ gammaT,
                                              unsigned int* __restrict__ hdec,
                                              const unsigned* __restrict__ np) {
  int i = blockIdx.x * 256 + threadIdx.x;  // pair index in [0, Bn*256)
  unsigned nb = np[0] << 8;
  unsigned key0 = nb * KC;
  unsigned key1 = (nb + 1u) * KC;
  int h = (i & 255) * 2;
  int b = i >> 8;
  float g0 = gammaT[(size_t)b * Hn + h];
  float g1 = gammaT[(size_t)b * Hn + h + 1];
  unsigned pay = (unsigned)f2bf(h0[h] * g0) | ((unsigned)f2bf(h0[h + 1] * g1) << 16);
  uint2* buf0 = (uint2*)hdec;
  uint2* buf1 = buf0 + (size_t)Bn * 256;
  uint2 v0; v0.x = pay; v0.y = pay ^ key0;
  uint2 v1; v1.x = 0u;  v1.y = key1 ^ 1u;
  buf0[i] = v0;
  buf1[i] = v1;
}

// Persistent MFMA scan: 256 blocks, 8 groups x 32 blocks (bt=blockIdx&7).
// Block owns 32 batches x 16 h-units. Weights bf16 in LDS.
//
// FLAG-FREE EXCHANGE (round 3, proven 530us): tagged dwordx2
// {pay, pay^key(run,t)}, sc0 sc1 fire-and-forget stores; consumers poll
// data and validate tags. Rounds 4/5 proved the ORDERING here is locally
// optimal (polls issued earlier -> round-0 misses -> slower). Byte-identical
// skeleton to round 3 except:
//
// ROUND 6: poll round-0 loads are sc0-ONLY (L1-bypass, served by the
// XCD-local L2, the intra-XCD coherence point). Group members
// (blockIdx = 8j+bt) land on one XCD under the dispatcher's round-robin,
// so producer sc0 sc1 stores are visible in the shared L2 at ~200cy
// instead of L3's ~700cy, and the 64KB/step/block poll traffic moves from
// L3 to L2 bandwidth. SELF-VALIDATING: if placement does not hold, the
// stale-L2 read simply fails tag validation and the retry loop re-reads
// with sc0 sc1 (the proven L3 path) -> no liveness/correctness dependence
// on placement; worst case is one fast extra round per step.
__global__ __launch_bounds__(256, 1) void k_scan(
    const unsigned short* __restrict__ xs_bf,  // [T,B,D] bf16
    const float* __restrict__ gammaT,          // [T,B,H] fp32
    unsigned int* __restrict__ hdec_tag,       // [2][B][256] x {pay,chk}
    unsigned short* __restrict__ h_bf,         // [T,B,H] bf16 (h1 history)
    const float* __restrict__ c0,              // [H]
    const float* __restrict__ W_ih,            // [4H, D] fp32
    const float* __restrict__ W_hh,            // [4H, H] fp32
    const float* __restrict__ b_ih, const float* __restrict__ b_hh,
    const float* __restrict__ tp,              // [B,T]
    const float* __restrict__ w_t, const float* __restrict__ h_t,
    const unsigned* __restrict__ np) {
  __shared__ unsigned short Wlds[64 * AP];  // 97 KB: 64 gate cols x 768 K
  __shared__ unsigned short Alds[32 * AP];  // 48.5 KB: 32 batches x 768 K
  __shared__ float Gs[32 * GS];             // 8.7 KB
  int tid = threadIdx.x;
  int bt = blockIdx.x & 7;   // batch group
  int ht = blockIdx.x >> 3;  // h tile [0,32)
  int b0 = bt * 32, h0b = ht * 16;
  unsigned nb = np[0] << 8;  // key base for this run

  // --- stage weights once: col c = g*16 + hu, K-major bf16
  for (int idx = tid; idx < 64 * 192; idx += 256) {
    int c = idx / 192;
    int s = idx - c * 192;
    int kg = s * 4;
    int g = c >> 4, hu = c & 15;
    int jw = g * Hn + h0b + hu;
    float4 wv;
    if (kg < Dn) wv = *(const float4*)(W_ih + (size_t)jw * Dn + kg);
    else         wv = *(const float4*)(W_hh + (size_t)jw * Hn + (kg - Dn));
    unsigned int u01 = (unsigned int)f2bf(wv.x) | ((unsigned int)f2bf(wv.y) << 16);
    unsigned int u23 = (unsigned int)f2bf(wv.z) | ((unsigned int)f2bf(wv.w) << 16);
    *(unsigned int*)(&Wlds[(size_t)c * AP + kg]) = u01;
    *(unsigned int*)(&Wlds[(size_t)c * AP + kg + 2]) = u23;
  }

  // --- per-thread cell hoists: thread -> (batch bl, h-pair hp)
  int bl = tid >> 3;
  int hp = tid & 7;
  int hloc = 2 * hp;
  int b = b0 + bl;
  float bias[4][2];
#pragma unroll
  for (int g = 0; g < 4; ++g)
#pragma unroll
    for (int u = 0; u < 2; ++u) {
      int jw = g * Hn + h0b + hloc + u;
      bias[g][u] = b_ih[jw] + b_hh[jw];
    }
  float wtv[2], htv[2], creg[2];
#pragma unroll
  for (int u = 0; u < 2; ++u) {
    wtv[u] = w_t[h0b + hloc + u];
    htv[u] = h_t[h0b + hloc + u];
    creg[u] = c0[h0b + hloc + u];
  }

  // --- MFMA lane mapping
  int lane = tid & 63, wv4 = tid >> 6;
  int ln = lane & 15, qd = lane >> 4;
  int mrow = 16 * (wv4 & 1) + ln;
  int ncol = 32 * (wv4 >> 1);
  const unsigned short* abase = &Alds[(size_t)mrow * AP + qd * 8];
  const unsigned short* bb0 = &Wlds[(size_t)(ncol + ln) * AP + qd * 8];
  const unsigned short* bb1 = &Wlds[(size_t)(ncol + 16 + ln) * AP + qd * 8];
  // producer store address (fixed h-pair, alternating parity)
  unsigned int* pstore =
      hdec_tag + ((size_t)b * 256 + 8 * (size_t)ht + hp) * 2;
  __syncthreads();

  for (int t = 0; t < Tn; ++t) {
    unsigned key = (nb + (unsigned)t) * KC;
    // --- prefetch epilogue operands (cached)
    float2 gam0 = *(const float2*)(gammaT + ((size_t)t * Bn + b) * Hn + h0b + hloc);
    float2 gam1 = (t + 1 < Tn)
        ? *(const float2*)(gammaT + ((size_t)(t + 1) * Bn + b) * Hn + h0b + hloc)
        : make_float2(0.f, 0.f);
    float tpv = tp[(size_t)b * Tn + t];

    // --- stage xs(t) rows (k < 256), cached loads
    {
      const float4* xsrc = (const float4*)(xs_bf + ((size_t)t * Bn + b0) * Dn);
#pragma unroll
      for (int i = 0; i < 4; ++i) {
        int c = tid + 256 * i;
        *(float4*)(&Alds[(size_t)(c >> 5) * AP + (c & 31) * 8]) = xsrc[c];
      }
    }

    // --- pull pre-decayed h via tagged poll
    // round 0: sc0-only (XCD-local L2). retries: sc0 sc1 (L3 fallback).
    {
      const unsigned int* hsrc =
          hdec_tag + (size_t)(t & 1) * (Bn * 256 * 2) + (size_t)b0 * 256 * 2;
      u32x4 hv[16];
#pragma unroll
      for (int i = 0; i < 16; ++i) {
        int q = tid + 256 * i;
        const void* p = hsrc + (size_t)q * 4;  // dwordx4 = 2 tagged pairs
        asm volatile("global_load_dwordx4 %0, %1, off sc0"
                     : "=&v"(hv[i]) : "v"(p) : "memory");
      }
      asm volatile("s_waitcnt vmcnt(0)" ::: "memory");
      __builtin_amdgcn_sched_barrier(0);
      int ok = 1;
#pragma unroll
      for (int i = 0; i < 16; ++i)
        ok &= (hv[i][1] == (hv[i][0] ^ key)) & (hv[i][3] == (hv[i][2] ^ key));
      int spins = 0;
      while (!ok) {
        if (++spins > 300000) break;  // bounded: visible failure, never hang
        __builtin_amdgcn_s_sleep(1);
#pragma unroll
        for (int i = 0; i < 16; ++i) {
          int q = tid + 256 * i;
          const void* p = hsrc + (size_t)q * 4;
          asm volatile("global_load_dwordx4 %0, %1, off sc0 sc1"
                       : "=&v"(hv[i]) : "v"(p) : "memory");
        }
        asm volatile("s_waitcnt vmcnt(0)" ::: "memory");
        __builtin_amdgcn_sched_barrier(0);
        ok = 1;
#pragma unroll
        for (int i = 0; i < 16; ++i)
          ok &= (hv[i][1] == (hv[i][0] ^ key)) & (hv[i][3] == (hv[i][2] ^ key));
      }
#pragma unroll
      for (int i = 0; i < 16; ++i) {
        int q = tid + 256 * i;
        int blr = q >> 7;            // batch row (128 chunks per batch)
        int p0 = (q & 127) * 2;      // first pair index in chunk
        uint2 pv; pv.x = hv[i][0]; pv.y = hv[i][2];
        *(uint2*)(&Alds[(size_t)blr * AP + 256 + 2 * p0]) = pv;
      }
    }
    __syncthreads();

    // --- MFMA: 24 k-steps x 2 n-tiles -> 16M x 32N per wave
    f32x4 acc0 = {0.f, 0.f, 0.f, 0.f};
    f32x4 acc1 = {0.f, 0.f, 0.f, 0.f};
#pragma unroll
    for (int ks = 0; ks < 24; ++ks) {
      bf8_t a = *(const bf8_t*)(abase + ks * 32);
      bf8_t b0f = *(const bf8_t*)(bb0 + ks * 32);
      bf8_t b1f = *(const bf8_t*)(bb1 + ks * 32);
      acc0 = __builtin_amdgcn_mfma_f32_16x16x32_bf16(a, b0f, acc0, 0, 0, 0);
      acc1 = __builtin_amdgcn_mfma_f32_16x16x32_bf16(a, b1f, acc1, 0, 0, 0);
    }

    // --- gates -> LDS (C layout: col=lane&15, row=quad*4+reg)
#pragma unroll
    for (int r = 0; r < 4; ++r) {
      int grow = 16 * (wv4 & 1) + qd * 4 + r;
      Gs[grow * GS + ncol + ln] = acc0[r];
      Gs[grow * GS + ncol + 16 + ln] = acc1[r];
    }
    __syncthreads();

    // --- LSTM cell: 2 adjacent-h cells per thread
    {
      float2 ip = *(const float2*)(&Gs[bl * GS + hloc]);
      float2 fp = *(const float2*)(&Gs[bl * GS + 16 + hloc]);
      float2 gp = *(const float2*)(&Gs[bl * GS + 32 + hloc]);
      float2 op = *(const float2*)(&Gs[bl * GS + 48 + hloc]);
      float h1[2], hd[2];
      float gam0a[2] = {gam0.x, gam0.y}, gam1a[2] = {gam1.x, gam1.y};
      float ipa[2] = {ip.x, ip.y}, fpa[2] = {fp.x, fp.y};
      float gpa[2] = {gp.x, gp.y}, opa[2] = {op.x, op.y};
#pragma unroll
      for (int u = 0; u < 2; ++u) {
        float c1 = sigm(fpa[u] + bias[1][u]) * (creg[u] * gam0a[u]) +
                   sigm(ipa[u] + bias[0][u]) * tanhf(gpa[u] + bias[2][u]);
        float gtv = sigm(tpv * wtv[u] + htv[u]);
        h1[u] = gtv * sigm(opa[u] + bias[3][u]) * tanhf(c1);
        creg[u] = gtv * c1;
        hd[u] = h1[u] * gam1a[u];
      }
      // fire-and-forget tagged store for step t+1 (no drain, no flag)
      if (t + 1 < Tn) {
        unsigned keyn = (nb + (unsigned)(t + 1)) * KC;
        unsigned dpk =
            (unsigned)f2bf(hd[0]) | ((unsigned)f2bf(hd[1]) << 16);
        unsigned long long val =
            (unsigned long long)dpk | ((unsigned long long)(dpk ^ keyn) << 32);
        const void* dp = pstore + (size_t)((t + 1) & 1) * (Bn * 256 * 2);
        asm volatile("global_store_dwordx2 %0, %1, off sc0 sc1"
                     :: "v"(dp), "v"(val) : "memory");
      }
      // h1 history (cached store; consumed only by k_head)
      unsigned hpk =
          (unsigned)f2bf(h1[0]) | ((unsigned)f2bf(h1[1]) << 16);
      *(unsigned int*)(h_bf + ((size_t)t * Bn + b) * Hn + h0b + hloc) = hpk;
    }
  }
}

// Batched output head over all (t,b) rows; h1 read from bf16 history
__global__ __launch_bounds__(256) void k_head(const unsigned short* __restrict__ h_bf,
                                              const float* __restrict__ W1,
                                              const float* __restrict__ b1,
                                              const float* __restrict__ W2,
                                              const float* __restrict__ b2,
                                              float* __restrict__ outs) {
  __shared__ float sW1[Hn * 10];
  for (int i = threadIdx.x; i < Hn * 10; i += 256) sW1[i] = W1[i];
  __syncthreads();
  int idx = blockIdx.x * 256 + threadIdx.x;  // idx = tt*Bn + b
  const uint4* row = (const uint4*)(h_bf + (size_t)idx * Hn);
  float z1[10];
#pragma unroll
  for (int k = 0; k < 10; ++k) z1[k] = b1[k];
  for (int hq = 0; hq < Hn / 8; ++hq) {
    uint4 u = row[hq];
    float hv[8];
    hv[0] = bf2f(u.x & 0xffff); hv[1] = bf2f(u.x >> 16);
    hv[2] = bf2f(u.y & 0xffff); hv[3] = bf2f(u.y >> 16);
    hv[4] = bf2f(u.z & 0xffff); hv[5] = bf2f(u.z >> 16);
    hv[6] = bf2f(u.w & 0xffff); hv[7] = bf2f(u.w >> 16);
    int hb = hq * 8;
#pragma unroll
    for (int c = 0; c < 8; ++c)
#pragma unroll
      for (int k = 0; k < 10; ++k) z1[k] += hv[c] * sW1[(hb + c) * 10 + k];
  }
#pragma unroll
  for (int k = 0; k < 10; ++k) z1[k] = sigm(z1[k]);
  float z2[2];
#pragma unroll
  for (int c = 0; c < 2; ++c) {
    float v = b2[c];
#pragma unroll
    for (int k = 0; k < 10; ++k) v += z1[k] * W2[k * 2 + c];
    z2[c] = sigm(v);
  }
  float mx = fmaxf(z2[0], z2[1]);
  float e0 = expf(z2[0] - mx), e1 = expf(z2[1] - mx);
  float s = e0 + e1;
  outs[(size_t)idx * 2 + 0] = e0 / s;
  outs[(size_t)idx * 2 + 1] = e1 / s;
}

}  // namespace

extern "C" void kernel_launch(void* const* d_in, const int* in_sizes, int n_in,
                              void* d_out, int out_size, void* d_ws,
                              size_t ws_size, hipStream_t stream) {
  (void)in_sizes; (void)n_in; (void)out_size; (void)ws_size;
  const float* x     = (const float*)d_in[0];
  const float* dt    = (const float*)d_in[1];
  const float* mask  = (const float*)d_in[2];
  const float* tp    = (const float*)d_in[3];
  const float* xmean = (const float*)d_in[4];
  const float* h0    = (const float*)d_in[5];
  const float* c0    = (const float*)d_in[6];
  const float* w_gx  = (const float*)d_in[7];
  const float* h_gx  = (const float*)d_in[8];
  const float* w_gh  = (const float*)d_in[9];
  const float* h_gh  = (const float*)d_in[10];
  const float* w_t   = (const float*)d_in[11];
  const float* h_t   = (const float*)d_in[12];
  const float* W_ih  = (const float*)d_in[13];
  const float* W_hh  = (const float*)d_in[14];
  const float* b_ih  = (const float*)d_in[15];
  const float* b_hh  = (const float*)d_in[16];
  const float* oW1   = (const float*)d_in[17];
  const float* ob1   = (const float*)d_in[18];
  const float* oW2   = (const float*)d_in[19];
  const float* ob2   = (const float*)d_in[20];

  float* out  = (float*)d_out;
  float* outs = out;                        // [T,B,2]
  float* xhat = out + (size_t)Tn * Bn * 2;  // [T,B,D] fp32 (output 1)

  float* ws = (float*)d_ws;
  float* gammaT = ws;  // [T,B,H] fp32: 67.1 MB
  unsigned short* xs_bf  = (unsigned short*)(gammaT + (size_t)BT * Hn);  // 16.8 MB
  unsigned short* h_bf   = xs_bf + (size_t)BT * Dn;                      // 33.6 MB
  unsigned int* hdec_tag = (unsigned int*)(h_bf + (size_t)BT * Hn);      // 1 MB
  unsigned short* dt_bf  = (unsigned short*)(hdec_tag + 2 * (size_t)Bn * 256 * 2);
  unsigned short* wghT   = dt_bf + (size_t)BT * Dn;                      // 0.26 MB
  unsigned* np = (unsigned*)(wghT + (size_t)Hn * Dn);                    // 4 B nonce

  k_nonce<<<1, 64, 0, stream>>>(np);
  k_cvt_dt<<<BT * Dn / 4 / 256, 256, 0, stream>>>(dt, dt_bf);
  k_cvt_wgh<<<Hn * Dn / 256, 256, 0, stream>>>(w_gh, wghT);
  k_gamma_mfma<<<dim3(Hn / 64, Bn), 256, 0, stream>>>(dt_bf, wghT, h_gh, gammaT);
  k_xs<<<dim3(Dn / 64, BT / 64), 256, 0, stream>>>(dt, w_gx, h_gx, x, mask,
                                                   xmean, xhat, xs_bf);
  k_init<<<(Bn * 256) / 256, 256, 0, stream>>>(h0, gammaT, hdec_tag, np);
  k_scan<<<256, 256, 0, stream>>>(xs_bf, gammaT, hdec_tag, h_bf, c0, W_ih, W_hh,
                                  b_ih, b_hh, tp, w_t, h_t, np);
  k_head<<<BT / 256, 256, 0, stream>>>(h_bf, oW1, ob1, oW2, ob2, outs);
}